// Round 6
// baseline (839.478 us; speedup 1.0000x reference)
//
#include <hip/hip_runtime.h>
#include <hip/hip_bf16.h>
#include <stdint.h>

#define D_MODEL 2048
#define D_FF    8192
#define NTOK    4096
#define WSCALE  0.02f

using bf16 = __hip_bfloat16;
typedef __bf16 bf16x8 __attribute__((ext_vector_type(8)));
typedef float  f32x4  __attribute__((ext_vector_type(4)));

// async global -> LDS, 16 B per lane (wave-uniform base + lane*16 layout)
__device__ __forceinline__ void gld_lds16(const bf16* g, bf16* l) {
    __builtin_amdgcn_global_load_lds((const __attribute__((address_space(1))) void*)g,
                                     (__attribute__((address_space(3))) void*)l,
                                     16, 0, 0);
}

// ---------------- standalone dequant (fallback when ws can't hold separate Wd) --------------
__global__ __launch_bounds__(256) void dequant_kernel(const int* __restrict__ walks,
                                                      const float* __restrict__ lut,
                                                      const float* __restrict__ sl,
                                                      const float* __restrict__ sr,
                                                      bf16* __restrict__ W,
                                                      int colsLog2) {
    __shared__ float slut[256];
    slut[threadIdx.x] = lut[threadIdx.x] * WSCALE;
    __syncthreads();
    long base = ((long)blockIdx.x * 256 + threadIdx.x) * 8;
    int r = (int)(base >> colsLog2);
    int c = (int)(base & ((1 << colsLog2) - 1));
    float s = sl[r];
    const int4* wp = (const int4*)(walks + base);
    int4 w0 = wp[0];
    int4 w1 = wp[1];
    float4 s0 = *(const float4*)(sr + c);
    float4 s1 = *(const float4*)(sr + c + 4);
    alignas(16) bf16 o[8];
    o[0] = __float2bfloat16(slut[w0.x] * s0.x * s);
    o[1] = __float2bfloat16(slut[w0.y] * s0.y * s);
    o[2] = __float2bfloat16(slut[w0.z] * s0.z * s);
    o[3] = __float2bfloat16(slut[w0.w] * s0.w * s);
    o[4] = __float2bfloat16(slut[w1.x] * s1.x * s);
    o[5] = __float2bfloat16(slut[w1.y] * s1.y * s);
    o[6] = __float2bfloat16(slut[w1.z] * s1.z * s);
    o[7] = __float2bfloat16(slut[w1.w] * s1.w * s);
    *(uint4*)(W + base) = *(const uint4*)o;
}

// ---------------- merged prep: x->bf16 + up to 3 dequants, one launch ----------------
__global__ __launch_bounds__(256) void prep_kernel(const float* __restrict__ x, bf16* __restrict__ xb,
    const int* __restrict__ wk_g, const float* __restrict__ lut_g,
    const float* __restrict__ sl_g, const float* __restrict__ sr_g, bf16* __restrict__ Wg,
    const int* __restrict__ wk_u, const float* __restrict__ lut_u,
    const float* __restrict__ sl_u, const float* __restrict__ sr_u, bf16* __restrict__ Wu,
    const int* __restrict__ wk_d, const float* __restrict__ lut_d,
    const float* __restrict__ sl_d, const float* __restrict__ sr_d, bf16* __restrict__ Wd) {
    const int t = threadIdx.x;
    const int b = blockIdx.x;
    if (b < 4096) {
        long base = ((long)b * 256 + t) * 8;
        float4 a = *(const float4*)(x + base);
        float4 v = *(const float4*)(x + base + 4);
        alignas(16) bf16 o[8];
        o[0] = __float2bfloat16(a.x); o[1] = __float2bfloat16(a.y);
        o[2] = __float2bfloat16(a.z); o[3] = __float2bfloat16(a.w);
        o[4] = __float2bfloat16(v.x); o[5] = __float2bfloat16(v.y);
        o[6] = __float2bfloat16(v.z); o[7] = __float2bfloat16(v.w);
        *(uint4*)(xb + base) = *(const uint4*)o;
        return;
    }
    const int* wk; const float* lut; const float* sl; const float* sr; bf16* W;
    int clog, bb;
    if (b < 12288)      { wk = wk_g; lut = lut_g; sl = sl_g; sr = sr_g; W = Wg; clog = 11; bb = b - 4096; }
    else if (b < 20480) { wk = wk_u; lut = lut_u; sl = sl_u; sr = sr_u; W = Wu; clog = 11; bb = b - 12288; }
    else                { wk = wk_d; lut = lut_d; sl = sl_d; sr = sr_d; W = Wd; clog = 13; bb = b - 20480; }
    __shared__ float slut[256];
    slut[t] = lut[t] * WSCALE;
    __syncthreads();
    long base = ((long)bb * 256 + t) * 8;
    int r = (int)(base >> clog);
    int c = (int)(base & ((1 << clog) - 1));
    float s = sl[r];
    const int4* wp = (const int4*)(wk + base);
    int4 w0 = wp[0];
    int4 w1 = wp[1];
    float4 s0 = *(const float4*)(sr + c);
    float4 s1 = *(const float4*)(sr + c + 4);
    alignas(16) bf16 o[8];
    o[0] = __float2bfloat16(slut[w0.x] * s0.x * s);
    o[1] = __float2bfloat16(slut[w0.y] * s0.y * s);
    o[2] = __float2bfloat16(slut[w0.z] * s0.z * s);
    o[3] = __float2bfloat16(slut[w0.w] * s0.w * s);
    o[4] = __float2bfloat16(slut[w1.x] * s1.x * s);
    o[5] = __float2bfloat16(slut[w1.y] * s1.y * s);
    o[6] = __float2bfloat16(slut[w1.z] * s1.z * s);
    o[7] = __float2bfloat16(slut[w1.w] * s1.w * s);
    *(uint4*)(W + base) = *(const uint4*)o;
}

// gateup LDS XOR swizzle, BK=64 (8 chunks of 8 bf16 per 128 B row):
//   chunk c of row r at slot (c + r) & 7. Verified R2/R4: conflicts 1.68e7 -> 5.2e5.
// NOTE: epilogue acc loops MUST stay fully unrolled — runtime idx -> scratch spill (R2).

// ---------------- fused gate+up GEMM, BK=64 (unchanged: ~287 us, ~955 TF) -------------
__global__ __launch_bounds__(256, 2) void gemm_gateup(const bf16* __restrict__ A,
                                                      const bf16* __restrict__ Bg_,
                                                      const bf16* __restrict__ Bu_,
                                                      bf16* __restrict__ G) {
    __shared__ alignas(16) char smem[49152];
    bf16* As  = (bf16*)smem;
    bf16* Bgs = (bf16*)(smem + 16384);
    bf16* Bus = (bf16*)(smem + 32768);

    const int t = threadIdx.x;
    const int mBase = blockIdx.y * 128;
    const int nBase = blockIdx.x * 128;
    const int K = D_MODEL;

    const int srow = t >> 3;
    const int colO = (((t & 7) - ((t >> 3) & 7)) & 7) * 8;
    const bf16* Ag  = A   + (long)(mBase + srow) * K + colO;
    const bf16* Bgg = Bg_ + (long)(nBase + srow) * K + colO;
    const bf16* Bug = Bu_ + (long)(nBase + srow) * K + colO;
    const long rstep = (long)32 * K;

    f32x4 accg[4][4], accu[4][4];
#pragma unroll
    for (int i = 0; i < 4; i++)
#pragma unroll
        for (int j = 0; j < 4; j++) {
            f32x4 z = {0.f, 0.f, 0.f, 0.f};
            accg[i][j] = z; accu[i][j] = z;
        }

    const int lane  = t & 63;
    const int wave  = t >> 6;
    const int waveM = (wave & 1) * 64;
    const int waveN = (wave >> 1) * 64;
    const int m16   = lane & 15;
    const int s0    = (((lane >> 4) + (m16 & 7)) & 7) * 8;
    const bf16* Asr0 = As  + (waveM + m16) * 64 + s0;
    const bf16* Bgr0 = Bgs + (waveN + m16) * 64 + s0;
    const bf16* Bur0 = Bus + (waveN + m16) * 64 + s0;
    const int sx = (s0 ^ 32) - s0;

    for (int k0 = 0; k0 < K; k0 += 64) {
#pragma unroll
        for (int p = 0; p < 4; p++) {
            gld_lds16(Ag  + k0 + p * rstep, As  + p * 2048 + t * 8);
            gld_lds16(Bgg + k0 + p * rstep, Bgs + p * 2048 + t * 8);
            gld_lds16(Bug + k0 + p * rstep, Bus + p * 2048 + t * 8);
        }
        __syncthreads();

#pragma unroll
        for (int ks = 0; ks < 2; ks++) {
            const int d = ks ? sx : 0;
            bf16x8 af[4], bg[4], bu[4];
#pragma unroll
            for (int i = 0; i < 4; i++) af[i] = *(const bf16x8*)(Asr0 + d + i * 1024);
#pragma unroll
            for (int j = 0; j < 4; j++) bg[j] = *(const bf16x8*)(Bgr0 + d + j * 1024);
#pragma unroll
            for (int j = 0; j < 4; j++) bu[j] = *(const bf16x8*)(Bur0 + d + j * 1024);
#pragma unroll
            for (int i = 0; i < 4; i++)
#pragma unroll
                for (int j = 0; j < 4; j++) {
                    accg[i][j] = __builtin_amdgcn_mfma_f32_16x16x32_bf16(af[i], bg[j], accg[i][j], 0, 0, 0);
                    accu[i][j] = __builtin_amdgcn_mfma_f32_16x16x32_bf16(af[i], bu[j], accu[i][j], 0, 0, 0);
                }
        }
        __syncthreads();
    }

    float* Tw = (float*)smem + wave * 1088;
    const int rq = (lane >> 4) * 4;
#pragma unroll
    for (int i = 0; i < 4; i++) {
#pragma unroll
        for (int j = 0; j < 4; j++)
#pragma unroll
            for (int r = 0; r < 4; r++) {
                float g = accg[i][j][r];
                float u = accu[i][j][r];
                float h = (g / (1.0f + __expf(-g))) * u;
                Tw[(rq + r) * 68 + j * 16 + m16] = h;
            }
        __syncthreads();
#pragma unroll
        for (int s = 0; s < 4; s++) {
            int row = (lane >> 4) + 4 * s;
            f32x4 v = *(const f32x4*)(Tw + row * 68 + (m16 << 2));
            union { ushort u16[4]; uint2 d; } o;
            o.u16[0] = __bfloat16_as_ushort(__float2bfloat16(v[0]));
            o.u16[1] = __bfloat16_as_ushort(__float2bfloat16(v[1]));
            o.u16[2] = __bfloat16_as_ushort(__float2bfloat16(v[2]));
            o.u16[3] = __bfloat16_as_ushort(__float2bfloat16(v[3]));
            long grow = mBase + waveM + i * 16 + row;
            int  gcol = nBase + waveN + (m16 << 2);
            *(uint2*)(G + grow * D_FF + gcol) = o.d;
        }
        __syncthreads();
    }
}

// ---------------- down GEMM, split-K=2, BK=64: Out += G @ Wd^T (fp32 atomics) ---------------
// R5 post-mortem: down at 512 blocks = exactly 2/CU resident, zero queue -> lockstep staging
// bursts, no de-phasing; BK 64->128 was neutral (not barrier-count-bound). Split K into 2
// segments -> 1024 blocks, 3/CU resident (32 KB LDS, launch_bounds(256,3)), partials combined
// via device-scope fp32 atomicAdd onto memset-zeroed d_out.
__global__ __launch_bounds__(256, 3) void gemm_down(const bf16* __restrict__ A,
                                                    const bf16* __restrict__ B,
                                                    float* __restrict__ Out) {
    __shared__ alignas(16) char smem[32768];   // 2 x 16 KB staging; epilogue T = 17408 B
    bf16* As = (bf16*)smem;
    bf16* Bs = (bf16*)(smem + 16384);

    const int t = threadIdx.x;
    const int mBase = blockIdx.y * 128;
    const int nBase = blockIdx.x * 128;
    const int K = D_FF;                        // full row stride
    const int kOff = blockIdx.z * (D_FF / 2);  // this block's K segment [kOff, kOff+4096)

    const int srow = t >> 3;
    const int colO = (((t & 7) - ((t >> 3) & 7)) & 7) * 8;
    const bf16* Ag = A + (long)(mBase + srow) * K + kOff + colO;
    const bf16* Bg = B + (long)(nBase + srow) * K + kOff + colO;
    const long rstep = (long)32 * K;

    f32x4 acc[4][4];
#pragma unroll
    for (int i = 0; i < 4; i++)
#pragma unroll
        for (int j = 0; j < 4; j++) {
            f32x4 z = {0.f, 0.f, 0.f, 0.f};
            acc[i][j] = z;
        }

    const int lane  = t & 63;
    const int wave  = t >> 6;
    const int waveM = (wave & 1) * 64;
    const int waveN = (wave >> 1) * 64;
    const int m16   = lane & 15;
    const int s0    = (((lane >> 4) + (m16 & 7)) & 7) * 8;
    const bf16* Asr0 = As + (waveM + m16) * 64 + s0;
    const bf16* Bsr0 = Bs + (waveN + m16) * 64 + s0;
    const int sx = (s0 ^ 32) - s0;

    for (int k0 = 0; k0 < D_FF / 2; k0 += 64) {
#pragma unroll
        for (int p = 0; p < 4; p++) {
            gld_lds16(Ag + k0 + p * rstep, As + p * 2048 + t * 8);
            gld_lds16(Bg + k0 + p * rstep, Bs + p * 2048 + t * 8);
        }
        __syncthreads();

#pragma unroll
        for (int ks = 0; ks < 2; ks++) {
            const int d = ks ? sx : 0;
            bf16x8 af[4], bfr[4];
#pragma unroll
            for (int i = 0; i < 4; i++) af[i]  = *(const bf16x8*)(Asr0 + d + i * 1024);
#pragma unroll
            for (int j = 0; j < 4; j++) bfr[j] = *(const bf16x8*)(Bsr0 + d + j * 1024);
#pragma unroll
            for (int i = 0; i < 4; i++)
#pragma unroll
                for (int j = 0; j < 4; j++)
                    acc[i][j] = __builtin_amdgcn_mfma_f32_16x16x32_bf16(af[i], bfr[j], acc[i][j], 0, 0, 0);
        }
        __syncthreads();
    }

    // epilogue: per-wave LDS transpose -> coalesced fp32 atomicAdd (4 dwords/lane, 256 B/row)
    float* Tw = (float*)smem + wave * 1088;
    const int rq = (lane >> 4) * 4;
#pragma unroll
    for (int i = 0; i < 4; i++) {
#pragma unroll
        for (int j = 0; j < 4; j++)
#pragma unroll
            for (int r = 0; r < 4; r++)
                Tw[(rq + r) * 68 + j * 16 + m16] = acc[i][j][r];
        __syncthreads();
#pragma unroll
        for (int s = 0; s < 4; s++) {
            int row = (lane >> 4) + 4 * s;
            f32x4 v = *(const f32x4*)(Tw + row * 68 + (m16 << 2));
            long grow = mBase + waveM + i * 16 + row;
            int  gcol = nBase + waveN + (m16 << 2);
            float* op = Out + grow * D_MODEL + gcol;
            atomicAdd(op + 0, v[0]);
            atomicAdd(op + 1, v[1]);
            atomicAdd(op + 2, v[2]);
            atomicAdd(op + 3, v[3]);
        }
        __syncthreads();
    }
}

extern "C" void kernel_launch(void* const* d_in, const int* in_sizes, int n_in,
                              void* d_out, int out_size, void* d_ws, size_t ws_size,
                              hipStream_t stream) {
    (void)in_sizes; (void)n_in;
    const float* x     = (const float*)d_in[0];
    const float* lut_g = (const float*)d_in[1];
    const float* lut_u = (const float*)d_in[2];
    const float* lut_d = (const float*)d_in[3];
    const int*   wk_g  = (const int*)d_in[4];
    const int*   wk_u  = (const int*)d_in[5];
    const int*   wk_d  = (const int*)d_in[6];
    const float* sl_g  = (const float*)d_in[7];
    const float* sr_g  = (const float*)d_in[8];
    const float* sl_u  = (const float*)d_in[9];
    const float* sr_u  = (const float*)d_in[10];
    const float* sl_d  = (const float*)d_in[11];
    const float* sr_d  = (const float*)d_in[12];

    char* ws = (char*)d_ws;
    bf16* xb = (bf16*)(ws);                                   // 16 MB
    bf16* Wg = (bf16*)(ws + (size_t)16 * 1024 * 1024);        // 32 MB
    bf16* Wu = (bf16*)(ws + (size_t)48 * 1024 * 1024);        // 32 MB
    bf16* G  = (bf16*)(ws + (size_t)80 * 1024 * 1024);        // 64 MB
    const bool sepWd = ws_size >= (size_t)176 * 1024 * 1024;
    bf16* Wd = sepWd ? (bf16*)(ws + (size_t)144 * 1024 * 1024) : Wg;
    float* out = (float*)d_out;

    // zero d_out for the split-K atomic accumulation (graph-capturable memset node)
    hipMemsetAsync(out, 0, (size_t)out_size * sizeof(float), stream);

    prep_kernel<<<dim3(sepWd ? 28672 : 20480), 256, 0, stream>>>(
        x, xb, wk_g, lut_g, sl_g, sr_g, Wg, wk_u, lut_u, sl_u, sr_u, Wu,
        wk_d, lut_d, sl_d, sr_d, sepWd ? Wd : nullptr);

    gemm_gateup<<<dim3(D_FF / 128, NTOK / 128), 256, 0, stream>>>(xb, Wg, Wu, G);

    if (!sepWd)
        dequant_kernel<<<dim3(D_MODEL * D_FF / 2048), 256, 0, stream>>>(wk_d, lut_d, sl_d, sr_d, Wd, 13);

    // down: out += G @ Wd^T, split-K=2, fp32 atomics
    gemm_down<<<dim3(D_MODEL / 128, NTOK / 128, 2), 256, 0, stream>>>(G, Wd, out);
}